// Round 5
// baseline (323.395 us; speedup 1.0000x reference)
//
#include <hip/hip_runtime.h>
#include <hip/hip_bf16.h>
#include <hip/hip_fp16.h>
#include <cstddef>
#include <cstdint>

#define T_ 4
#define B_ 16
#define N_ 512
#define C_ 512
#define H_ 8
#define D_ 64
#define BN_T (B_*N_)   // 8192

typedef unsigned short u16;
typedef __attribute__((ext_vector_type(8))) short bf16x8;       // 8 bf16
typedef __attribute__((ext_vector_type(8))) _Float16 f16x8;     // 8 fp16
typedef __attribute__((ext_vector_type(8))) unsigned short u16x8;
typedef __attribute__((ext_vector_type(4))) float f32x4;

__device__ __forceinline__ u16 f2bf_exact(float f) {
    union { float f; unsigned u; } x; x.f = f; return (u16)(x.u >> 16);
}
// 2-term exact fp16 split: f == h1 + h2/2048 + tail(<=2^-22|f|)
__device__ __forceinline__ void split2(float f, u16& h1, u16& h2) {
    const __half a = __float2half(f);                   // RNE
    const float r = (f - __half2float(a)) * 2048.0f;    // exact (Sterbenz + pow2)
    const __half b = __float2half(r);
    h1 = __half_as_ushort(a); h2 = __half_as_ushort(b);
}
// XOR swizzle, 16B granularity, BYTE offset into a [128][32] fp16 tile (64B rows)
__device__ __forceinline__ int swz(int rr, int q) {
    return (rr << 6) + (((q ^ ((rr >> 1) & 3)) & 3) << 4);
}
// attention LDS swizzle (element index into [64][64] u16 tiles)
__device__ __forceinline__ int SW(int row, int col) {
    return (row << 6) + (col ^ ((row & 7) << 3));
}
// async global->LDS, 16B per lane (dest = uniform base + lane*16)
__device__ __forceinline__ void gload16(const void* g, void* l) {
    __builtin_amdgcn_global_load_lds(
        (const __attribute__((address_space(1))) unsigned int*)g,
        (__attribute__((address_space(3))) unsigned int*)l, 16, 0, 0);
}

// ---------------------------------------------------------------------------
// x fp32 [T,BN,C] -> tile-major pre-swizzled fp16 splits x1t, x2t.
// ---------------------------------------------------------------------------
__global__ __launch_bounds__(256) void k_split_x(
    const float* __restrict__ x, u16* __restrict__ x1t, u16* __restrict__ x2t)
{
    const int tile = blockIdx.x;            // mt*16 + kb  (4096 tiles)
    const int mt = tile >> 4, kb = tile & 15;
    const int tid = threadIdx.x;
    const int rr = tid >> 1, kh = tid & 1;
    const int t = rr & 3, bn = mt * 32 + (rr >> 2);
    const float* src = x + ((size_t)t * BN_T + bn) * C_ + kb * 32 + kh * 16;
    float f[16];
    *reinterpret_cast<float4*>(f + 0)  = *reinterpret_cast<const float4*>(src + 0);
    *reinterpret_cast<float4*>(f + 4)  = *reinterpret_cast<const float4*>(src + 4);
    *reinterpret_cast<float4*>(f + 8)  = *reinterpret_cast<const float4*>(src + 8);
    *reinterpret_cast<float4*>(f + 12) = *reinterpret_cast<const float4*>(src + 12);
    char* d1 = (char*)(x1t + ((size_t)tile << 12));
    char* d2 = (char*)(x2t + ((size_t)tile << 12));
    #pragma unroll
    for (int j = 0; j < 2; ++j) {
        u16x8 p1, p2;
        #pragma unroll
        for (int e = 0; e < 8; ++e) { u16 h1, h2; split2(f[8*j+e], h1, h2); p1[e] = h1; p2[e] = h2; }
        const int q = 2 * kh + j;
        *reinterpret_cast<u16x8*>(d1 + swz(rr, q)) = p1;
        *reinterpret_cast<u16x8*>(d2 + swz(rr, q)) = p2;
    }
}

// w fp32 [512][512] -> tile-major pre-swizzled fp16 splits
__global__ __launch_bounds__(256) void k_split_w(
    const float* __restrict__ w, u16* __restrict__ w1t, u16* __restrict__ w2t)
{
    const int tile = blockIdx.x;            // nt*16 + kb  (64 tiles)
    const int nt = tile >> 4, kb = tile & 15;
    const int tid = threadIdx.x;
    const int rr = tid >> 1, kh = tid & 1;
    const int c = nt * 128 + rr;
    const float* src = w + (size_t)c * C_ + kb * 32 + kh * 16;
    float f[16];
    *reinterpret_cast<float4*>(f + 0)  = *reinterpret_cast<const float4*>(src + 0);
    *reinterpret_cast<float4*>(f + 4)  = *reinterpret_cast<const float4*>(src + 4);
    *reinterpret_cast<float4*>(f + 8)  = *reinterpret_cast<const float4*>(src + 8);
    *reinterpret_cast<float4*>(f + 12) = *reinterpret_cast<const float4*>(src + 12);
    char* d1 = (char*)(w1t + ((size_t)tile << 12));
    char* d2 = (char*)(w2t + ((size_t)tile << 12));
    #pragma unroll
    for (int j = 0; j < 2; ++j) {
        u16x8 p1, p2;
        #pragma unroll
        for (int e = 0; e < 8; ++e) { u16 h1, h2; split2(f[8*j+e], h1, h2); p1[e] = h1; p2[e] = h2; }
        const int q = 2 * kh + j;
        *reinterpret_cast<u16x8*>(d1 + swz(rr, q)) = p1;
        *reinterpret_cast<u16x8*>(d2 + swz(rr, q)) = p2;
    }
}

// ---------------------------------------------------------------------------
// Split-fp16 MFMA Linear -> BN(eval) -> LIF over T=4 (unchanged round 4).
// ---------------------------------------------------------------------------
template<int MODE>
__global__ __launch_bounds__(256, 2) void k_linear_mfma(
    const u16* __restrict__ a1t, const u16* __restrict__ a2t,
    const u16* __restrict__ w1t, const u16* __restrict__ w2t,
    const float* __restrict__ bias, const float* __restrict__ gamma,
    const float* __restrict__ beta, const float* __restrict__ mean,
    const float* __restrict__ var, void* __restrict__ outp)
{
    __shared__ u16 lds[2][4][4096];   // [buf][A1,A2,B1,B2][8KB tile]

    const int dd  = blockIdx.x;                    // 0..1023
    const int lid = (dd & 7) * 128 + (dd >> 3);    // XCD swizzle (bijective)
    const int mt  = lid >> 2;                      // 0..255
    const int nt  = lid & 3;
    const int bn0 = mt * 32;
    const int c0  = nt * 128;

    const int tid = threadIdx.x;
    const int wv  = tid >> 6, lane = tid & 63;
    const int l15 = tid & 15, g = (tid & 63) >> 4;
    const int go  = wv * 2048 + lane * 16;   // per-lane byte offset in tile
    const int lo  = wv * 2048;               // wave-uniform LDS byte offset

    f32x4 accA[2][8], accB[2][8];
    #pragma unroll
    for (int rt = 0; rt < 2; ++rt)
        #pragma unroll
        for (int ct = 0; ct < 8; ++ct) { accA[rt][ct] = {0,0,0,0}; accB[rt][ct] = {0,0,0,0}; }

    const size_t abase = (size_t)mt * 16, bbase = (size_t)nt * 16;

    auto stage = [&](int buf, int kb) {
        char* L = (char*)&lds[buf][0][0];
        const char* ga1 = (const char*)(a1t + ((abase + kb) << 12)) + go;
        const char* gb1 = (const char*)(w1t + ((bbase + kb) << 12)) + go;
        const char* gb2 = (const char*)(w2t + ((bbase + kb) << 12)) + go;
        gload16(ga1,        L + lo);
        gload16(ga1 + 1024, L + lo + 1024);
        if (MODE == 0) {
            const char* ga2 = (const char*)(a2t + ((abase + kb) << 12)) + go;
            gload16(ga2,        L + 8192 + lo);
            gload16(ga2 + 1024, L + 8192 + lo + 1024);
        }
        gload16(gb1,        L + 16384 + lo);
        gload16(gb1 + 1024, L + 16384 + lo + 1024);
        gload16(gb2,        L + 24576 + lo);
        gload16(gb2 + 1024, L + 24576 + lo + 1024);
    };

    stage(0, 0);
    __syncthreads();

    #pragma unroll 1
    for (int kb = 0; kb < 16; ++kb) {
        const int buf = kb & 1;
        if (kb < 15) stage(buf ^ 1, kb + 1);       // async, flies under MFMAs
        const char* L = (const char*)&lds[buf][0][0];
        f16x8 a1[2], a2[2];
        #pragma unroll
        for (int rt = 0; rt < 2; ++rt) {
            const int rr = wv * 32 + rt * 16 + l15;
            a1[rt] = *reinterpret_cast<const f16x8*>(L + swz(rr, g));
            if (MODE == 0)
                a2[rt] = *reinterpret_cast<const f16x8*>(L + 8192 + swz(rr, g));
        }
        #pragma unroll
        for (int ct = 0; ct < 8; ++ct) {
            const int rr2 = ct * 16 + l15;
            const f16x8 b1 = *reinterpret_cast<const f16x8*>(L + 16384 + swz(rr2, g));
            const f16x8 b2 = *reinterpret_cast<const f16x8*>(L + 24576 + swz(rr2, g));
            #pragma unroll
            for (int rt = 0; rt < 2; ++rt) {
                accA[rt][ct] = __builtin_amdgcn_mfma_f32_16x16x32_f16(a1[rt], b1, accA[rt][ct], 0, 0, 0);
                if (MODE == 0)
                    accB[rt][ct] = __builtin_amdgcn_mfma_f32_16x16x32_f16(a2[rt], b1, accB[rt][ct], 0, 0, 0);
                accB[rt][ct] = __builtin_amdgcn_mfma_f32_16x16x32_f16(a1[rt], b2, accB[rt][ct], 0, 0, 0);
            }
        }
        __syncthreads();
    }

    // epilogue: reconstruct -> bias -> BN -> LIF(v_th=1) over reg r==t
    #pragma unroll
    for (int ct = 0; ct < 8; ++ct) {
        const int c = c0 + ct * 16 + l15;
        const float rs = 1.0f / sqrtf(var[c] + 1e-5f);
        const float ga = gamma[c], be = beta[c], mu = mean[c], bi = bias[c];
        #pragma unroll
        for (int rt = 0; rt < 2; ++rt) {
            const int bn = bn0 + wv * 8 + rt * 4 + g;
            float vm = 0.f;
            #pragma unroll
            for (int r = 0; r < 4; ++r) {
                const float y = accA[rt][ct][r] + accB[rt][ct][r] * (1.0f / 2048.0f) + bi;
                const float ybn = (y - mu) * rs * ga + be;
                const float h = vm + (ybn - vm) * 0.5f;
                const bool sp = (h >= 1.0f);
                vm = sp ? 0.f : h;
                if (MODE == 0) {
                    const int b = bn >> 9, n = bn & 511;
                    const int hh = c >> 6, d2 = c & 63;
                    ((u16*)outp)[((((size_t)r * B_ + b) * H_ + hh) * N_ + n) * D_ + d2] = sp ? 0x3F80 : 0;
                } else {
                    ((float*)outp)[((size_t)r * BN_T + bn) * C_ + c] = sp ? 1.0f : 0.0f;
                }
            }
        }
    }
}

// ---------------------------------------------------------------------------
// MFMA attention + LIF(0.5), cross-tile pipelined.
// Block = 8 waves (512 thr), one bh, 128 q-rows (wave w -> rows 16w..16w+15).
// K/V double-buffered in LDS; S strips double-buffered per wave; QK(j+1) and
// PV(j) run between the same barrier pair (two independent MFMA chains), so
// the S LDS round-trip hides under PV of the previous tile. Waves 0-3 stage
// K, waves 4-7 stage V (register prefetch -> LDS write).
// S kept as exact integers <=64 (bf16-exact); the 0.125 scale is folded into
// the LIF epilogue (pow-2, exact) -> bit-identical to the verified pipeline.
// ---------------------------------------------------------------------------
__global__ __launch_bounds__(512, 4) void k_attn_mfma(
    const u16* __restrict__ qg, const u16* __restrict__ kg,
    const u16* __restrict__ vg, u16* __restrict__ s2t)
{
    __shared__ u16 ks[2][4096];      // K tiles  [kv][d], swizzled
    __shared__ u16 vts[2][4096];     // V^T tiles [d][kv], swizzled
    __shared__ u16 ssb[8][2][1024];  // per-wave S strips [16 q][64 kv], swizzled

    const int id  = blockIdx.x;                 // 0..511
    const int lid = (id & 7) * 64 + (id >> 3);  // XCD swizzle (bijective)
    const int bh  = lid >> 2;                   // 0..127
    const int qt  = lid & 3;                    // q-tile of 128 rows
    const int b   = bh >> 3, hh = bh & 7;

    const int tid  = threadIdx.x;
    const int w    = tid >> 6, lane = tid & 63;
    const int l15  = lane & 15, g = lane >> 4;

    // staging roles: waves 0-3 -> K, waves 4-7 -> V
    const bool isK = (tid < 256);
    const int st   = isK ? tid : tid - 256;
    const int krow = st >> 4, kcol = (st & 15) * 4;   // K coords
    const int vkv  = (st & 15) * 4, vd = (st >> 4) * 4; // V coords

    ushort4 pre[4];          // prefetched K rows or V rows
    bf16x8 qa[2];

    f32x4 vmem[4], oacc[4];
    #pragma unroll
    for (int d0 = 0; d0 < 4; ++d0) vmem[d0] = {0,0,0,0};

    #pragma unroll 1
    for (int t = 0; t < T_; ++t) {
        const size_t base = ((size_t)t * (B_ * H_) + bh) * (size_t)(N_ * D_);

        auto prefetch = [&](int j2) {
            const int m0 = j2 * 64;
            if (isK) {
                #pragma unroll
                for (int i = 0; i < 4; ++i)
                    pre[i] = *reinterpret_cast<const ushort4*>(
                        kg + base + (size_t)(m0 + krow + 16 * i) * D_ + kcol);
            } else {
                #pragma unroll
                for (int i = 0; i < 4; ++i)
                    pre[i] = *reinterpret_cast<const ushort4*>(
                        vg + base + (size_t)(m0 + vkv + i) * D_ + vd);
            }
        };
        auto ldswrite = [&](int buf) {
            if (isK) {
                #pragma unroll
                for (int i = 0; i < 4; ++i)
                    *reinterpret_cast<ushort4*>(&ks[buf][SW(krow + 16 * i, kcol)]) = pre[i];
            } else {
                #pragma unroll
                for (int j = 0; j < 4; ++j) {
                    ushort4 wv4;
                    wv4.x = (&pre[0].x)[j]; wv4.y = (&pre[1].x)[j];
                    wv4.z = (&pre[2].x)[j]; wv4.w = (&pre[3].x)[j];
                    *reinterpret_cast<ushort4*>(&vts[buf][SW(vd + j, vkv)]) = wv4;
                }
            }
        };
        auto qk = [&](int kbuf, int sbuf) {
            u16* sb = &ssb[w][sbuf][0];
            #pragma unroll
            for (int kvt = 0; kvt < 4; ++kvt) {
                f32x4 acc = {0.f, 0.f, 0.f, 0.f};
                #pragma unroll
                for (int c = 0; c < 2; ++c) {
                    const bf16x8 kb = *reinterpret_cast<const bf16x8*>(
                        &ks[kbuf][SW(16 * kvt + l15, 32 * c + 8 * g)]);
                    acc = __builtin_amdgcn_mfma_f32_16x16x32_bf16(qa[c], kb, acc, 0, 0, 0);
                }
                #pragma unroll
                for (int r = 0; r < 4; ++r)
                    sb[SW(4 * g + r, 16 * kvt + l15)] = f2bf_exact(acc[r]); // int <=64, exact
            }
        };
        auto pv = [&](int vbuf, int sbuf) {
            const u16* sb = &ssb[w][sbuf][0];
            #pragma unroll
            for (int c = 0; c < 2; ++c) {
                const bf16x8 sa = *reinterpret_cast<const bf16x8*>(
                    &sb[SW(l15, 32 * c + 8 * g)]);
                #pragma unroll
                for (int d0 = 0; d0 < 4; ++d0) {
                    const bf16x8 vb = *reinterpret_cast<const bf16x8*>(
                        &vts[vbuf][SW(16 * d0 + l15, 32 * c + 8 * g)]);
                    oacc[d0] = __builtin_amdgcn_mfma_f32_16x16x32_bf16(sa, vb, oacc[d0], 0, 0, 0);
                }
            }
        };

        // prologue
        prefetch(0);
        {
            const size_t qrow = base + (size_t)(qt * 128 + 16 * w + l15) * D_;
            qa[0] = *reinterpret_cast<const bf16x8*>(qg + qrow + 8 * g);
            qa[1] = *reinterpret_cast<const bf16x8*>(qg + qrow + 32 + 8 * g);
        }
        #pragma unroll
        for (int d0 = 0; d0 < 4; ++d0) oacc[d0] = {0.f, 0.f, 0.f, 0.f};
        ldswrite(0);
        __syncthreads();
        prefetch(1);
        qk(0, 0);

        // steady state: PV(j) overlaps QK(j+1) and staging of KV(j+2)
        #pragma unroll 1
        for (int j = 0; j < 7; ++j) {
            ldswrite((j + 1) & 1);
            __syncthreads();
            if (j < 6) prefetch(j + 2);
            qk((j + 1) & 1, (j + 1) & 1);
            pv(j & 1, j & 1);
            __syncthreads();
        }
        pv(1, 1);

        // LIF (v_th=0.5); 0.125 scale folded here (pow2, exact); tiled s2t out
        #pragma unroll
        for (int d0 = 0; d0 < 4; ++d0) {
            const int c = hh * 64 + d0 * 16 + l15;
            const int kb2 = c >> 5, kq = (c >> 3) & 3, e = c & 7;
            #pragma unroll
            for (int r = 0; r < 4; ++r) {
                const float o = oacc[d0][r] * 0.125f;
                const float h = vmem[d0][r] + (o - vmem[d0][r]) * 0.5f;
                const bool sp = (h >= 0.5f);
                vmem[d0][r] = sp ? 0.f : h;
                const int n = qt * 128 + 16 * w + 4 * g + r;
                const int bn = b * 512 + n;
                const int mt2 = bn >> 5;
                const int rr2 = (bn & 31) * 4 + t;
                const size_t off = (((size_t)mt2 * 16 + kb2) << 13) + (rr2 << 6)
                                 + (((kq ^ ((rr2 >> 1) & 3)) & 3) << 4) + (e << 1);
                *(u16*)((char*)s2t + off) = sp ? 0x3C00 : 0;   // fp16 1.0
            }
        }
    }
}

extern "C" void kernel_launch(void* const* d_in, const int* in_sizes, int n_in,
                              void* d_out, int out_size, void* d_ws, size_t ws_size,
                              hipStream_t stream)
{
    const float* x = (const float*)d_in[0];
    const float* W[4]  = {(const float*)d_in[1],  (const float*)d_in[7],  (const float*)d_in[13], (const float*)d_in[19]};
    const float* Bi[4] = {(const float*)d_in[2],  (const float*)d_in[8],  (const float*)d_in[14], (const float*)d_in[20]};
    const float* Ga[4] = {(const float*)d_in[3],  (const float*)d_in[9],  (const float*)d_in[15], (const float*)d_in[21]};
    const float* Be[4] = {(const float*)d_in[4],  (const float*)d_in[10], (const float*)d_in[16], (const float*)d_in[22]};
    const float* Mu[4] = {(const float*)d_in[5],  (const float*)d_in[11], (const float*)d_in[17], (const float*)d_in[23]};
    const float* Va[4] = {(const float*)d_in[6],  (const float*)d_in[12], (const float*)d_in[18], (const float*)d_in[24]};

    const size_t SPK = (size_t)T_ * B_ * N_ * C_;   // 16,777,216
    const size_t WSZ = (size_t)C_ * C_;             // 262,144
    u16* qb  = (u16*)d_ws;          // bf16 spikes [T,B,H,N,D]
    u16* kbf = qb + SPK;
    u16* vbf = kbf + SPK;
    u16* x1t = vbf + SPK;           // tiled x1; reused as s2t after linears
    u16* x2t = x1t + SPK;           // tiled x2
    u16* wt  = x2t + SPK;           // 4 weights x 2 splits x WSZ
    u16* s2t = x1t;                 // attn output overlays x1t (dead by then)

    dim3 blk(256);
    k_split_x<<<4096, blk, 0, stream>>>(x, x1t, x2t);
    for (int i = 0; i < 4; ++i)
        k_split_w<<<64, blk, 0, stream>>>(W[i], wt + (2*i) * WSZ, wt + (2*i+1) * WSZ);

    k_linear_mfma<0><<<1024, blk, 0, stream>>>(x1t, x2t, wt + 0*WSZ, wt + 1*WSZ, Bi[0], Ga[0], Be[0], Mu[0], Va[0], qb);
    k_linear_mfma<0><<<1024, blk, 0, stream>>>(x1t, x2t, wt + 2*WSZ, wt + 3*WSZ, Bi[1], Ga[1], Be[1], Mu[1], Va[1], kbf);
    k_linear_mfma<0><<<1024, blk, 0, stream>>>(x1t, x2t, wt + 4*WSZ, wt + 5*WSZ, Bi[2], Ga[2], Be[2], Mu[2], Va[2], vbf);
    k_attn_mfma<<<512, dim3(512), 0, stream>>>(qb, kbf, vbf, s2t);
    k_linear_mfma<1><<<1024, blk, 0, stream>>>(s2t, x2t, wt + 6*WSZ, wt + 7*WSZ, Bi[3], Ga[3], Be[3], Mu[3], Va[3], d_out);
}